// Round 21
// baseline (181.194 us; speedup 1.0000x reference)
//
#include <hip/hip_runtime.h>
#include <hip/hip_bf16.h>

// MultiScaleRetention forward, MI355X gfx950 — Round 21.
// R20: 178.0 µs (best). This round, two low-risk tweaks:
// (1) T5 s_setprio(1/0) around retention's QK and PV MFMA clusters — the two
//     co-resident blocks per CU run independent phases (m191 regime, +4-7%).
// (2) qkvg g-epilogue routed through the proven LDS bounce (coalesced u32
//     stores instead of 64 scalar 2B stores/thread).
// All else R20-byte-identical.

#define B_ 2
#define T_ 2048
#define E_ 1024
#define V_ 2048
#define H_ 8
#define KD_ 128
#define HD_ 256
#define M_ 4096  // B_*T_

typedef __attribute__((ext_vector_type(8))) short bf16x8;
typedef __attribute__((ext_vector_type(4))) float f32x4;

__device__ __forceinline__ float u2f(unsigned short u) {
    return __uint_as_float(((unsigned)u) << 16);
}
__device__ __forceinline__ unsigned short f2bu(float f) {
    unsigned x = __float_as_uint(f);
    return (unsigned short)((x + 0x7fffu + ((x >> 16) & 1u)) >> 16);  // RNE
}

typedef const __attribute__((address_space(1))) void gas_t;
typedef __attribute__((address_space(3))) void las_t;
__device__ __forceinline__ void gl_lds16(const void* g, void* l) {
    __builtin_amdgcn_global_load_lds((gas_t*)g, (las_t*)l, 16, 0, 0);
}

// ---------------------------------------------------------------------------
// Packed weight transpose incl. Wo, PLUS x->bf16 conversion (z=5). [R20]
// ---------------------------------------------------------------------------
__global__ __launch_bounds__(256) void transW6_kernel(
    const float* __restrict__ Wq, const float* __restrict__ Wk,
    const float* __restrict__ Wv, const float* __restrict__ Wg,
    const float* __restrict__ Wo, const float* __restrict__ x,
    unsigned short* __restrict__ Wt, unsigned short* __restrict__ wot,
    unsigned short* __restrict__ xb)
{
    const int z = blockIdx.z;
    const int tid = threadIdx.x;
    if (z == 5) {
        const int bid = (int)blockIdx.y * 32 + (int)blockIdx.x;   // 0..1023
        const size_t base = (size_t)bid * 4096 + (size_t)tid * 16;
        #pragma unroll
        for (int j = 0; j < 2; ++j) {
            const size_t i = base + j * 8;
            float4 a = *(const float4*)(x + i);
            float4 c = *(const float4*)(x + i + 4);
            *(ushort4*)(xb + i)     = make_ushort4(f2bu(a.x), f2bu(a.y), f2bu(a.z), f2bu(a.w));
            *(ushort4*)(xb + i + 4) = make_ushort4(f2bu(c.x), f2bu(c.y), f2bu(c.z), f2bu(c.w));
        }
        return;
    }
    const float* W; int N; int rofs; int Kd; unsigned short* dst;
    if (z == 0)      { W = Wq; N = 1024; rofs = 0;    Kd = 1024; dst = Wt; }
    else if (z == 1) { W = Wk; N = 1024; rofs = 1024; Kd = 1024; dst = Wt; }
    else if (z == 2) { W = Wv; N = 2048; rofs = 2048; Kd = 1024; dst = Wt; }
    else if (z == 3) { W = Wg; N = 2048; rofs = 4096; Kd = 1024; dst = Wt; }
    else             { W = Wo; N = 1024; rofs = 0;    Kd = 2048; dst = wot; }
    const int n0 = blockIdx.x * 64;
    const int k0 = blockIdx.y * 64;
    if (n0 >= N || k0 >= Kd) return;

    __shared__ float tl[64][65];
    #pragma unroll
    for (int i = 0; i < 4; ++i) {
        int kr = i * 16 + (tid >> 4);
        int nc = (tid & 15) * 4;
        float4 v = *(const float4*)(W + (size_t)(k0 + kr) * N + n0 + nc);
        tl[kr][nc] = v.x; tl[kr][nc + 1] = v.y; tl[kr][nc + 2] = v.z; tl[kr][nc + 3] = v.w;
    }
    __syncthreads();
    #pragma unroll
    for (int i = 0; i < 4; ++i) {
        int nr = i * 16 + (tid >> 4);
        int kc = (tid & 15) * 4;
        ushort4 u = make_ushort4(f2bu(tl[kc + 0][nr]), f2bu(tl[kc + 1][nr]),
                                 f2bu(tl[kc + 2][nr]), f2bu(tl[kc + 3][nr]));
        *(ushort4*)(dst + (size_t)(rofs + n0 + nr) * Kd + k0 + kc) = u;
    }
}

// ---------------------------------------------------------------------------
// GEMM stage + compute building blocks (dbuf pipeline).  [R9 verbatim]
// ---------------------------------------------------------------------------
#define GSTAGE(BUF, K0)                                                        \
    {                                                                          \
        _Pragma("unroll")                                                      \
        for (int i = 0; i < 4; ++i) {                                          \
            int r = i * 32 + srow;                                             \
            int cb = scolb ^ ((r & 7) << 4);                                   \
            gl_lds16((const char*)(A  + (size_t)(rowBase + r) * K + (K0)) + cb,\
                     Asm[BUF] + i * 4096 + w * 1024);                          \
            gl_lds16((const char*)(Bt + (size_t)(colBase + r) * K + (K0)) + cb,\
                     Bsm[BUF] + i * 4096 + w * 1024);                          \
        }                                                                      \
    }

#define GCOMPUTE(BUF)                                                          \
    {                                                                          \
        _Pragma("unroll")                                                      \
        for (int kk = 0; kk < 2; ++kk) {                                       \
            const int cb = kk * 64 + (l >> 4) * 16;                            \
            bf16x8 a[4], b[4];                                                 \
            _Pragma("unroll")                                                  \
            for (int m = 0; m < 4; ++m) {                                      \
                int r = wr * 64 + m * 16 + (l & 15);                           \
                a[m] = *(const bf16x8*)(Asm[BUF] + r * 128 + (cb ^ ((r & 7) << 4))); \
            }                                                                  \
            _Pragma("unroll")                                                  \
            for (int n = 0; n < 4; ++n) {                                      \
                int r = wc * 64 + n * 16 + (l & 15);                           \
                b[n] = *(const bf16x8*)(Bsm[BUF] + r * 128 + (cb ^ ((r & 7) << 4))); \
            }                                                                  \
            _Pragma("unroll")                                                  \
            for (int m = 0; m < 4; ++m)                                        \
                _Pragma("unroll")                                              \
                for (int n = 0; n < 4; ++n)                                    \
                    acc[m][n] = __builtin_amdgcn_mfma_f32_16x16x32_bf16(a[m], b[n], acc[m][n], 0, 0, 0); \
        }                                                                      \
    }

#define GEMM_PIPELINE_LOOP                                                     \
    GSTAGE(0, 0)                                                               \
    const int nk = K / 64;                                                     \
    for (int kt = 0; kt < nk; ++kt) {                                          \
        const int cur = kt & 1;                                                \
        if (kt + 1 < nk) {                                                     \
            GSTAGE(1 - cur, (kt + 1) * 64)                                     \
            asm volatile("s_waitcnt vmcnt(8)" ::: "memory");                   \
        } else {                                                               \
            asm volatile("s_waitcnt vmcnt(0)" ::: "memory");                   \
        }                                                                      \
        __builtin_amdgcn_s_barrier();                                          \
        __builtin_amdgcn_sched_barrier(0);                                     \
        GCOMPUTE(cur)                                                          \
        __builtin_amdgcn_s_barrier();                                          \
        __builtin_amdgcn_sched_barrier(0);                                     \
    }

// ---------------------------------------------------------------------------
// Fused q,k,v,g GEMM with theta epilogue; g now via coalesced LDS bounce.
// ---------------------------------------------------------------------------
__global__ __launch_bounds__(256) void gemm_qkvg_kernel(
    const unsigned short* __restrict__ A,
    const unsigned short* __restrict__ Bt,
    const float* __restrict__ sinp,
    const float* __restrict__ cosp,
    unsigned short* __restrict__ qb,
    unsigned short* __restrict__ kb,
    unsigned short* __restrict__ vt,
    unsigned short* __restrict__ gb)
{
    const int K = E_;
    __shared__ __align__(16) char pool[65536];
    char (*Asm)[16384] = (char(*)[16384])pool;
    char (*Bsm)[16384] = (char(*)[16384])(pool + 32768);
    const int tid = threadIdx.x;
    const int l = tid & 63;
    const int w = tid >> 6;
    const int wr = w >> 1, wc = w & 1;
    const int rowBase = blockIdx.y * 128;
    const int colBase = blockIdx.x * 128;
    const int srow = tid >> 3;
    const int scolb = (tid & 7) * 16;

    f32x4 acc[4][4] = {};

    GEMM_PIPELINE_LOOP

    if (colBase < 2048) {
        // q or k: theta applied to fp32 acc via LDS bounce.  [R18 verbatim]
        float* scr = (float*)pool;
        #pragma unroll
        for (int m = 0; m < 4; ++m)
            #pragma unroll
            for (int n = 0; n < 4; ++n)
                #pragma unroll
                for (int r = 0; r < 4; ++r) {
                    int row = wr * 64 + m * 16 + (l >> 4) * 4 + r;
                    int colL = wc * 64 + n * 16 + (l & 15);
                    scr[row * 128 + (colL ^ ((row & 7) << 2))] = acc[m][n][r];
                }
        __syncthreads();
        const float scale = (colBase < 1024) ? 1.0f : 0.088388347648318447f;
        unsigned short* dst = (colBase < 1024) ? qb : kb;
        const int cbase = (colBase < 1024) ? colBase : (colBase - 1024);
        const int pr = tid & 63;
        const int rr = tid >> 6;
        #pragma unroll 4
        for (int i = 0; i < 32; ++i) {
            const int row = i * 4 + rr;
            const int rowG = rowBase + row;
            const int col0 = 2 * pr;
            float2 p = *(float2*)(scr + row * 128 + (col0 ^ ((row & 7) << 2)));
            const int sb = (rowG & (T_ - 1)) * KD_ + col0;
            float2 sv = *(const float2*)(sinp + sb);
            float2 cv = *(const float2*)(cosp + sb);
            float o0 = (p.x * cv.x - p.y * sv.x) * scale;
            float o1 = (p.y * cv.y + p.x * sv.y) * scale;
            if (!isfinite(o0)) o0 = 0.f;
            if (!isfinite(o1)) o1 = 0.f;
            unsigned u = (unsigned)f2bu(o0) | ((unsigned)f2bu(o1) << 16);
            *(unsigned*)(dst + (size_t)rowG * E_ + cbase + col0) = u;
        }
    } else if (colBase < 4096) {
        // v: transposed store into vt  [R17 verbatim]
        const int colW = colBase + wc * 64;
        #pragma unroll
        for (int m = 0; m < 4; ++m)
            #pragma unroll
            for (int n = 0; n < 4; ++n) {
                const int row0 = rowBase + wr * 64 + m * 16 + (l >> 4) * 4;
                const int vcol = colW + n * 16 + (l & 15) - 2048;
                const int vbatch = row0 >> 11;
                const int t0 = row0 & (T_ - 1);
                unsigned short pk[4];
                #pragma unroll
                for (int r = 0; r < 4; ++r) {
                    float f = acc[m][n][r];
                    if (!isfinite(f)) f = 0.f;
                    pk[r] = f2bu(f);
                }
                *(ushort4*)(vt + (size_t)(vbatch * V_ + vcol) * T_ + t0) =
                    make_ushort4(pk[0], pk[1], pk[2], pk[3]);
            }
    } else {
        // g: LDS bounce -> coalesced u32 stores (same pattern as q/k, no theta)
        float* scr = (float*)pool;
        #pragma unroll
        for (int m = 0; m < 4; ++m)
            #pragma unroll
            for (int n = 0; n < 4; ++n)
                #pragma unroll
                for (int r = 0; r < 4; ++r) {
                    int row = wr * 64 + m * 16 + (l >> 4) * 4 + r;
                    int colL = wc * 64 + n * 16 + (l & 15);
                    scr[row * 128 + (colL ^ ((row & 7) << 2))] = acc[m][n][r];
                }
        __syncthreads();
        const int cbase = colBase - 4096;
        const int pr = tid & 63;
        const int rr = tid >> 6;
        #pragma unroll 4
        for (int i = 0; i < 32; ++i) {
            const int row = i * 4 + rr;
            const int rowG = rowBase + row;
            const int col0 = 2 * pr;
            float2 p = *(float2*)(scr + row * 128 + (col0 ^ ((row & 7) << 2)));
            float o0 = p.x, o1 = p.y;
            if (!isfinite(o0)) o0 = 0.f;   // tripwire
            if (!isfinite(o1)) o1 = 0.f;
            unsigned u = (unsigned)f2bu(o0) | ((unsigned)f2bu(o1) << 16);
            *(unsigned*)(gb + (size_t)rowG * V_ + cbase + col0) = u;
        }
    }
}

// ---------------------------------------------------------------------------
// Wo GEMM, 64x128 tile.  [R20 verbatim — 2D grid (8,64)]
// ---------------------------------------------------------------------------
__global__ __launch_bounds__(256) void gemm_wo_kernel(
    const unsigned short* __restrict__ A,
    const unsigned short* __restrict__ Bt,
    float* __restrict__ C)
{
    const int K = V_;   // 2048
    __shared__ __align__(16) char Asm[2][64 * 128];
    __shared__ __align__(16) char Bsm[2][128 * 128];
    const int tid = threadIdx.x;
    const int l = tid & 63;
    const int w = tid >> 6;
    const int wr = w >> 1, wc = w & 1;
    const int rowBase = blockIdx.y * 64;
    const int colBase = blockIdx.x * 128;
    const int srow = tid >> 3;
    const int scolb = (tid & 7) * 16;

    f32x4 acc[2][4] = {};

#define WSTAGE(BUF, K0)                                                        \
    {                                                                          \
        _Pragma("unroll")                                                      \
        for (int i = 0; i < 2; ++i) {                                          \
            int r = i * 32 + srow;                                             \
            int cb = scolb ^ ((r & 7) << 4);                                   \
            gl_lds16((const char*)(A + (size_t)(rowBase + r) * K + (K0)) + cb, \
                     Asm[BUF] + i * 4096 + w * 1024);                          \
        }                                                                      \
        _Pragma("unroll")                                                      \
        for (int i = 0; i < 4; ++i) {                                          \
            int r = i * 32 + srow;                                             \
            int cb = scolb ^ ((r & 7) << 4);                                   \
            gl_lds16((const char*)(Bt + (size_t)(colBase + r) * K + (K0)) + cb,\
                     Bsm[BUF] + i * 4096 + w * 1024);                          \
        }                                                                      \
    }

    WSTAGE(0, 0)
    const int nk = K / 64;   // 32
    for (int kt = 0; kt < nk; ++kt) {
        const int cur = kt & 1;
        if (kt + 1 < nk) {
            WSTAGE(1 - cur, (kt + 1) * 64)
            asm volatile("s_waitcnt vmcnt(6)" ::: "memory");
        } else {
            asm volatile("s_waitcnt vmcnt(0)" ::: "memory");
        }
        __builtin_amdgcn_s_barrier();
        __builtin_amdgcn_sched_barrier(0);
        #pragma unroll
        for (int kk = 0; kk < 2; ++kk) {
            const int cb = kk * 64 + (l >> 4) * 16;
            bf16x8 a[2], b[4];
            #pragma unroll
            for (int m = 0; m < 2; ++m) {
                int r = wr * 32 + m * 16 + (l & 15);
                a[m] = *(const bf16x8*)(Asm[cur] + r * 128 + (cb ^ ((r & 7) << 4)));
            }
            #pragma unroll
            for (int n = 0; n < 4; ++n) {
                int r = wc * 64 + n * 16 + (l & 15);
                b[n] = *(const bf16x8*)(Bsm[cur] + r * 128 + (cb ^ ((r & 7) << 4)));
            }
            #pragma unroll
            for (int m = 0; m < 2; ++m)
                #pragma unroll
                for (int n = 0; n < 4; ++n)
                    acc[m][n] = __builtin_amdgcn_mfma_f32_16x16x32_bf16(a[m], b[n], acc[m][n], 0, 0, 0);
        }
        __builtin_amdgcn_s_barrier();
        __builtin_amdgcn_sched_barrier(0);
    }
#undef WSTAGE

    #pragma unroll
    for (int m = 0; m < 2; ++m)
        #pragma unroll
        for (int n = 0; n < 4; ++n)
            #pragma unroll
            for (int r = 0; r < 4; ++r) {
                int row = rowBase + wr * 32 + m * 16 + (l >> 4) * 4 + r;
                int col = colBase + wc * 64 + n * 16 + (l & 15);
                float f = acc[m][n][r];
                if (!isfinite(f)) f = 0.f;
                C[(size_t)row * E_ + col] = f;
            }
}

// ---------------------------------------------------------------------------
// Retention v6 + T5 setprio around MFMA clusters.  [else R20 verbatim]
// ---------------------------------------------------------------------------
#define STAGE_K(BUF, T0)                                                       \
    {                                                                          \
        _Pragma("unroll")                                                      \
        for (int i = 0; i < 4; ++i) {                                          \
            int r = i * 16 + (tid >> 4);                                       \
            int cb = ((tid & 15) * 16) ^ ((r & 7) << 4);                       \
            gl_lds16((const char*)(kb + (size_t)(b * T_ + (T0) + r) * E_ + h * KD_) + cb, \
                     Ks[BUF] + i * 4096 + w * 1024);                           \
        }                                                                      \
    }

#define STAGE_V(T0)                                                            \
    {                                                                          \
        _Pragma("unroll")                                                      \
        for (int i = 0; i < 8; ++i) {                                          \
            int r = i * 32 + (tid >> 3);                                       \
            int cb = ((tid & 7) * 16) ^ ((r & 7) << 4);                        \
            gl_lds16((const char*)(vt + (size_t)((b * H_ + h) * HD_ + r) * T_ + (T0)) + cb, \
                     Vs + i * 4096 + w * 1024);                                \
        }                                                                      \
    }

__global__ __launch_bounds__(256, 2) void retention_mfma_kernel(
    const unsigned short* __restrict__ qb,
    const unsigned short* __restrict__ kb,
    const unsigned short* __restrict__ vt,
    const unsigned short* __restrict__ g,
    unsigned short* __restrict__ ao)
{
    __shared__ __align__(16) char Ks[2][64 * 128 * 2];   // 2 x 16 KB
    __shared__ __align__(16) char Vs[256 * 64 * 2];      //     32 KB
    __shared__ __align__(16) char Pq[64 * 64 * 2];       //      8 KB [q][t]
    __shared__ float rsum_p[4][64];
    __shared__ float rsq_p[4][64];
    const int tid = threadIdx.x;
    const int l = tid & 63;
    const int w = tid >> 6;
    const int g_ = l >> 4;
    const int q15 = l & 15;
    const int orig = (int)blockIdx.x;
    const int xcd  = orig & 7;
    const int pos  = orig >> 3;
    const int slot = pos >> 5;
    const int cu   = pos & 31;
    const int half = cu >> 4;
    const int c15  = cu & 15;
    const int bh   = xcd * 2 + half;
    const int chunk = slot ? c15 : (31 - c15);
    const int b = bh >> 3, h = bh & 7;
    const int s0 = chunk * 64;
    const float ld = logf(1.f - exp2f(-5.f - (float)h));

    float es[4];
    #pragma unroll
    for (int qb2 = 0; qb2 < 4; ++qb2)
        es[qb2] = __expf((float)(s0 + qb2 * 16 + q15) * ld);
    float etl[4];
    #pragma unroll
    for (int r = 0; r < 4; ++r)
        etl[r] = __expf(-(float)(w * 16 + 4 * g_ + r) * ld);
    const float Dm64 = __expf(-64.f * ld);
    float etb = 1.f;

    bf16x8 qf[4][4];
    #pragma unroll
    for (int qb2 = 0; qb2 < 4; ++qb2) {
        const char* qp = (const char*)(qb + (size_t)(b * T_ + s0 + qb2 * 16 + q15) * E_ + h * KD_);
        #pragma unroll
        for (int kk = 0; kk < 4; ++kk)
            qf[qb2][kk] = *(const bf16x8*)(qp + kk * 64 + g_ * 16);
    }

    f32x4 oaccT[4][4] = {};
    float rs[4] = {0.f, 0.f, 0.f, 0.f};

    const int nt = chunk + 1;
    STAGE_K(0, 0)

    for (int t = 0; t < nt; ++t) {
        const int cur = t & 1;
        const int t0 = t * 64;
        STAGE_V(t0)
        if (t + 1 < nt) {
            STAGE_K(1 - cur, t0 + 64)
            asm volatile("s_waitcnt vmcnt(12)" ::: "memory");
        } else {
            asm volatile("s_waitcnt vmcnt(8)" ::: "memory");
        }
        __builtin_amdgcn_s_barrier();
        __builtin_amdgcn_sched_barrier(0);

        f32x4 sacc[4] = {};
        {
            const int krow = w * 16 + q15;
            const int swz = (krow & 7) << 4;
            __builtin_amdgcn_s_setprio(1);
            #pragma unroll
            for (int kk = 0; kk < 4; ++kk) {
                bf16x8 kf = *(const bf16x8*)(Ks[cur] + krow * 256 + ((kk * 64 + g_ * 16) ^ swz));
                #pragma unroll
                for (int qb2 = 0; qb2 < 4; ++qb2)
                    sacc[qb2] = __builtin_amdgcn_mfma_f32_16x16x32_bf16(kf, qf[qb2][kk], sacc[qb2], 0, 0, 0);
            }
            __builtin_amdgcn_s_setprio(0);
        }
        {
            const float etw = etb;
            #pragma unroll
            for (int qb2 = 0; qb2 < 4; ++qb2) {
                const int qg = s0 + qb2 * 16 + q15;
                const int q_local = qb2 * 16 + q15;
                float rsp = 0.f;
                unsigned short pk[4];
                #pragma unroll
                for (int r = 0; r < 4; ++r) {
                    int tg = t0 + w * 16 + 4 * g_ + r;
                    float pm = (qg >= tg) ? sacc[qb2][r] * (es[qb2] * etw * etl[r]) : 0.f;
                    rsp += pm;
                    pk[r] = f2bu(pm);
                }
                *(ushort4*)(Pq + q_local * 128 + (((w * 16 + 4 * g_) * 2) ^ ((q_local & 7) << 4))) =
                    make_ushort4(pk[0], pk[1], pk[2], pk[3]);
                rsp += __shfl_xor(rsp, 16);
                rsp += __shfl_xor(rsp, 32);
                rs[qb2] += rsp;
            }
            etb *= Dm64;
        }
        if (t + 1 < nt) {
            asm volatile("s_waitcnt vmcnt(4) lgkmcnt(0)" ::: "memory");
        } else {
            asm volatile("s_waitcnt vmcnt(0) lgkmcnt(0)" ::: "memory");
        }
        __builtin_amdgcn_s_barrier();
        __builtin_amdgcn_sched_barrier(0);
        __builtin_amdgcn_s_setprio(1);
        #pragma unroll
        for (int kk = 0; kk < 2; ++kk) {
            const int cb = kk * 64 + g_ * 16;
            bf16x8 pf[4], vf[4];
            #pragma unroll
            for (int qb2 = 0; qb2 < 4; ++qb2) {
                int pr = qb2 * 16 + q15;
                pf[qb2] = *(const bf16x8*)(Pq + pr * 128 + (cb ^ ((pr & 7) << 4)));
            }
            #pragma unroll
            for (int m = 0; m < 4; ++m) {
                int vr = w * 64 + m * 16 + q15;
                vf[m] = *(const bf16x8*)(Vs + vr * 128 + (cb ^ ((vr & 7) << 4)));
            }
            #pragma unroll
            for (int qb2 = 0; qb2 < 4; ++qb2)
                #pragma unroll
                for (int m = 0; m < 4; ++m)
                    oaccT[qb2][m] = __builtin_amdgcn_mfma_f32_16x16x32_bf16(vf[m], pf[qb2], oaccT[qb2][m], 0, 0, 0);
        }
        __builtin_amdgcn_s_setprio(0);
        __builtin_amdgcn_s_barrier();
        __builtin_amdgcn_sched_barrier(0);
    }

    if (l < 16) {
        #pragma unroll
        for (int qb2 = 0; qb2 < 4; ++qb2)
            rsum_p[w][qb2 * 16 + q15] = rs[qb2];
    }
    __syncthreads();

    float inv[4];
    #pragma unroll
    for (int qb2 = 0; qb2 < 4; ++qb2) {
        const int q_local = qb2 * 16 + q15;
        const float tot = rsum_p[0][q_local] + rsum_p[1][q_local] +
                          rsum_p[2][q_local] + rsum_p[3][q_local];
        inv[qb2] = 1.f / fmaxf(fabsf(tot), 1.f);
    }

    #pragma unroll
    for (int qb2 = 0; qb2 < 4; ++qb2) {
        float ps = 0.f;
        #pragma unroll
        for (int m = 0; m < 4; ++m)
            #pragma unroll
            for (int r = 0; r < 4; ++r) {
                float o = oaccT[qb2][m][r] * inv[qb2];
                ps += o * o;
            }
        ps += __shfl_xor(ps, 16);
        ps += __shfl_xor(ps, 32);
        if (l < 16) rsq_p[w][qb2 * 16 + q15] = ps;
    }
    __syncthreads();

    #pragma unroll
    for (int qb2 = 0; qb2 < 4; ++qb2) {
        const int q_local = qb2 * 16 + q15;
        const float tot = rsq_p[0][q_local] + rsq_p[1][q_local] +
                          rsq_p[2][q_local] + rsq_p[3][q_local];
        const float scale = rsqrtf(tot * (1.0f / HD_) + 1e-6f) * inv[qb2];
        const size_t rowb = (size_t)(b * T_ + s0 + q_local) * V_ + h * HD_;
        #pragma unroll
        for (int m = 0; m < 4; ++m) {
            const int vc0 = w * 64 + m * 16 + 4 * g_;
            ushort4 gv4 = *(const ushort4*)(g + rowb + vc0);
            const unsigned short* gv = (const unsigned short*)&gv4;
            unsigned short outp[4];
            #pragma unroll
            for (int r = 0; r < 4; ++r) {
                const float gvf = u2f(gv[r]);
                const float silu = gvf / (1.f + __expf(-gvf));
                float f = oaccT[qb2][m][r] * scale * silu;
                if (!isfinite(f)) f = 0.f;
                outp[r] = f2bu(f);
            }
            *(ushort4*)(ao + rowb + vc0) = make_ushort4(outp[0], outp[1], outp[2], outp[3]);
        }
    }
}

extern "C" void kernel_launch(void* const* d_in, const int* in_sizes, int n_in,
                              void* d_out, int out_size, void* d_ws, size_t ws_size,
                              hipStream_t stream)
{
    const float* x    = (const float*)d_in[0];
    const float* sinp = (const float*)d_in[1];
    const float* cosp = (const float*)d_in[2];
    // d_in[3] = mask: decay computed analytically in-kernel
    const float* Wq   = (const float*)d_in[4];
    const float* Wk   = (const float*)d_in[5];
    const float* Wv   = (const float*)d_in[6];
    const float* Wg   = (const float*)d_in[7];
    const float* Wo   = (const float*)d_in[8];
    float* out = (float*)d_out;

    // d_out doubles as scratch (R4-proven): xb [0,8.39M) | qb [8.39M,16.78M).
    unsigned short* xb = (unsigned short*)d_out;
    unsigned short* qb = xb + (size_t)M_ * E_;

    // ws: DISJOINT layout (~75 MB of 512 MiB).
    char* ws = (char*)d_ws;
    unsigned short* kb  = (unsigned short*)(ws + 0);         //  8.39 MB
    unsigned short* gb  = (unsigned short*)(ws + 8388608);   // 16.78 MB
    unsigned short* wt  = (unsigned short*)(ws + 25165824);  // 12.58 MB [6144][1024]
    unsigned short* vt  = (unsigned short*)(ws + 37748736);  // 16.78 MB [B*2048][T]
    unsigned short* aob = (unsigned short*)(ws + 54525952);  // 16.78 MB
    unsigned short* wot = (unsigned short*)(ws + 71303168);  //  4.19 MB

    dim3 blk(256);
    transW6_kernel<<<dim3(32, 32, 6), blk, 0, stream>>>(Wq, Wk, Wv, Wg, Wo, x, wt, wot, xb);

    gemm_qkvg_kernel<<<dim3(48, 32), blk, 0, stream>>>(xb, wt, sinp, cosp, qb, kb, vt, gb);

    retention_mfma_kernel<<<dim3(512), blk, 0, stream>>>(qb, kb, vt, gb, aob);

    gemm_wo_kernel<<<dim3(8, 64), blk, 0, stream>>>(aob, wot, out);
}

// Round 22
// 177.253 us; speedup vs baseline: 1.0222x; 1.0222x over previous
//
#include <hip/hip_runtime.h>
#include <hip/hip_bf16.h>

// MultiScaleRetention forward, MI355X gfx950 — Round 22 (= R20 verbatim).
// R21's setprio + g-bounce tweaks were null-to-negative (181.2 vs 178.0);
// both reverted per post-mortem discipline. This is the proven-best config:
// 4 dispatches — transW6 (weights+Wo transpose + x->bf16), qkvg GEMM (2-phase
// dbuf, theta-fused epilogue, v stored transposed), retention v6 (swapped
// operands, column PV, complementarity pairing, fused rms_silu), wo GEMM.

#define B_ 2
#define T_ 2048
#define E_ 1024
#define V_ 2048
#define H_ 8
#define KD_ 128
#define HD_ 256
#define M_ 4096  // B_*T_

typedef __attribute__((ext_vector_type(8))) short bf16x8;
typedef __attribute__((ext_vector_type(4))) float f32x4;

__device__ __forceinline__ float u2f(unsigned short u) {
    return __uint_as_float(((unsigned)u) << 16);
}
__device__ __forceinline__ unsigned short f2bu(float f) {
    unsigned x = __float_as_uint(f);
    return (unsigned short)((x + 0x7fffu + ((x >> 16) & 1u)) >> 16);  // RNE
}

typedef const __attribute__((address_space(1))) void gas_t;
typedef __attribute__((address_space(3))) void las_t;
__device__ __forceinline__ void gl_lds16(const void* g, void* l) {
    __builtin_amdgcn_global_load_lds((gas_t*)g, (las_t*)l, 16, 0, 0);
}

// ---------------------------------------------------------------------------
// Packed weight transpose incl. Wo, PLUS x->bf16 conversion (z=5).
// ---------------------------------------------------------------------------
__global__ __launch_bounds__(256) void transW6_kernel(
    const float* __restrict__ Wq, const float* __restrict__ Wk,
    const float* __restrict__ Wv, const float* __restrict__ Wg,
    const float* __restrict__ Wo, const float* __restrict__ x,
    unsigned short* __restrict__ Wt, unsigned short* __restrict__ wot,
    unsigned short* __restrict__ xb)
{
    const int z = blockIdx.z;
    const int tid = threadIdx.x;
    if (z == 5) {
        const int bid = (int)blockIdx.y * 32 + (int)blockIdx.x;   // 0..1023
        const size_t base = (size_t)bid * 4096 + (size_t)tid * 16;
        #pragma unroll
        for (int j = 0; j < 2; ++j) {
            const size_t i = base + j * 8;
            float4 a = *(const float4*)(x + i);
            float4 c = *(const float4*)(x + i + 4);
            *(ushort4*)(xb + i)     = make_ushort4(f2bu(a.x), f2bu(a.y), f2bu(a.z), f2bu(a.w));
            *(ushort4*)(xb + i + 4) = make_ushort4(f2bu(c.x), f2bu(c.y), f2bu(c.z), f2bu(c.w));
        }
        return;
    }
    const float* W; int N; int rofs; int Kd; unsigned short* dst;
    if (z == 0)      { W = Wq; N = 1024; rofs = 0;    Kd = 1024; dst = Wt; }
    else if (z == 1) { W = Wk; N = 1024; rofs = 1024; Kd = 1024; dst = Wt; }
    else if (z == 2) { W = Wv; N = 2048; rofs = 2048; Kd = 1024; dst = Wt; }
    else if (z == 3) { W = Wg; N = 2048; rofs = 4096; Kd = 1024; dst = Wt; }
    else             { W = Wo; N = 1024; rofs = 0;    Kd = 2048; dst = wot; }
    const int n0 = blockIdx.x * 64;
    const int k0 = blockIdx.y * 64;
    if (n0 >= N || k0 >= Kd) return;

    __shared__ float tl[64][65];
    #pragma unroll
    for (int i = 0; i < 4; ++i) {
        int kr = i * 16 + (tid >> 4);
        int nc = (tid & 15) * 4;
        float4 v = *(const float4*)(W + (size_t)(k0 + kr) * N + n0 + nc);
        tl[kr][nc] = v.x; tl[kr][nc + 1] = v.y; tl[kr][nc + 2] = v.z; tl[kr][nc + 3] = v.w;
    }
    __syncthreads();
    #pragma unroll
    for (int i = 0; i < 4; ++i) {
        int nr = i * 16 + (tid >> 4);
        int kc = (tid & 15) * 4;
        ushort4 u = make_ushort4(f2bu(tl[kc + 0][nr]), f2bu(tl[kc + 1][nr]),
                                 f2bu(tl[kc + 2][nr]), f2bu(tl[kc + 3][nr]));
        *(ushort4*)(dst + (size_t)(rofs + n0 + nr) * Kd + k0 + kc) = u;
    }
}

// ---------------------------------------------------------------------------
// GEMM stage + compute building blocks (dbuf pipeline).
// ---------------------------------------------------------------------------
#define GSTAGE(BUF, K0)                                                        \
    {                                                                          \
        _Pragma("unroll")                                                      \
        for (int i = 0; i < 4; ++i) {                                          \
            int r = i * 32 + srow;                                             \
            int cb = scolb ^ ((r & 7) << 4);                                   \
            gl_lds16((const char*)(A  + (size_t)(rowBase + r) * K + (K0)) + cb,\
                     Asm[BUF] + i * 4096 + w * 1024);                          \
            gl_lds16((const char*)(Bt + (size_t)(colBase + r) * K + (K0)) + cb,\
                     Bsm[BUF] + i * 4096 + w * 1024);                          \
        }                                                                      \
    }

#define GCOMPUTE(BUF)                                                          \
    {                                                                          \
        _Pragma("unroll")                                                      \
        for (int kk = 0; kk < 2; ++kk) {                                       \
            const int cb = kk * 64 + (l >> 4) * 16;                            \
            bf16x8 a[4], b[4];                                                 \
            _Pragma("unroll")                                                  \
            for (int m = 0; m < 4; ++m) {                                      \
                int r = wr * 64 + m * 16 + (l & 15);                           \
                a[m] = *(const bf16x8*)(Asm[BUF] + r * 128 + (cb ^ ((r & 7) << 4))); \
            }                                                                  \
            _Pragma("unroll")                                                  \
            for (int n = 0; n < 4; ++n) {                                      \
                int r = wc * 64 + n * 16 + (l & 15);                           \
                b[n] = *(const bf16x8*)(Bsm[BUF] + r * 128 + (cb ^ ((r & 7) << 4))); \
            }                                                                  \
            _Pragma("unroll")                                                  \
            for (int m = 0; m < 4; ++m)                                        \
                _Pragma("unroll")                                              \
                for (int n = 0; n < 4; ++n)                                    \
                    acc[m][n] = __builtin_amdgcn_mfma_f32_16x16x32_bf16(a[m], b[n], acc[m][n], 0, 0, 0); \
        }                                                                      \
    }

#define GEMM_PIPELINE_LOOP                                                     \
    GSTAGE(0, 0)                                                               \
    const int nk = K / 64;                                                     \
    for (int kt = 0; kt < nk; ++kt) {                                          \
        const int cur = kt & 1;                                                \
        if (kt + 1 < nk) {                                                     \
            GSTAGE(1 - cur, (kt + 1) * 64)                                     \
            asm volatile("s_waitcnt vmcnt(8)" ::: "memory");                   \
        } else {                                                               \
            asm volatile("s_waitcnt vmcnt(0)" ::: "memory");                   \
        }                                                                      \
        __builtin_amdgcn_s_barrier();                                          \
        __builtin_amdgcn_sched_barrier(0);                                     \
        GCOMPUTE(cur)                                                          \
        __builtin_amdgcn_s_barrier();                                          \
        __builtin_amdgcn_sched_barrier(0);                                     \
    }

// ---------------------------------------------------------------------------
// Fused q,k,v,g GEMM with theta epilogue.  [2D grid (48,32)]
// ---------------------------------------------------------------------------
__global__ __launch_bounds__(256) void gemm_qkvg_kernel(
    const unsigned short* __restrict__ A,
    const unsigned short* __restrict__ Bt,
    const float* __restrict__ sinp,
    const float* __restrict__ cosp,
    unsigned short* __restrict__ qb,
    unsigned short* __restrict__ kb,
    unsigned short* __restrict__ vt,
    unsigned short* __restrict__ gb)
{
    const int K = E_;
    __shared__ __align__(16) char pool[65536];
    char (*Asm)[16384] = (char(*)[16384])pool;
    char (*Bsm)[16384] = (char(*)[16384])(pool + 32768);
    const int tid = threadIdx.x;
    const int l = tid & 63;
    const int w = tid >> 6;
    const int wr = w >> 1, wc = w & 1;
    const int rowBase = blockIdx.y * 128;
    const int colBase = blockIdx.x * 128;
    const int srow = tid >> 3;
    const int scolb = (tid & 7) * 16;

    f32x4 acc[4][4] = {};

    GEMM_PIPELINE_LOOP

    if (colBase < 2048) {
        // q or k: theta applied to fp32 acc via LDS bounce.
        float* scr = (float*)pool;
        #pragma unroll
        for (int m = 0; m < 4; ++m)
            #pragma unroll
            for (int n = 0; n < 4; ++n)
                #pragma unroll
                for (int r = 0; r < 4; ++r) {
                    int row = wr * 64 + m * 16 + (l >> 4) * 4 + r;
                    int colL = wc * 64 + n * 16 + (l & 15);
                    scr[row * 128 + (colL ^ ((row & 7) << 2))] = acc[m][n][r];
                }
        __syncthreads();
        const float scale = (colBase < 1024) ? 1.0f : 0.088388347648318447f;
        unsigned short* dst = (colBase < 1024) ? qb : kb;
        const int cbase = (colBase < 1024) ? colBase : (colBase - 1024);
        const int pr = tid & 63;
        const int rr = tid >> 6;
        #pragma unroll 4
        for (int i = 0; i < 32; ++i) {
            const int row = i * 4 + rr;
            const int rowG = rowBase + row;
            const int col0 = 2 * pr;
            float2 p = *(float2*)(scr + row * 128 + (col0 ^ ((row & 7) << 2)));
            const int sb = (rowG & (T_ - 1)) * KD_ + col0;
            float2 sv = *(const float2*)(sinp + sb);
            float2 cv = *(const float2*)(cosp + sb);
            float o0 = (p.x * cv.x - p.y * sv.x) * scale;
            float o1 = (p.y * cv.y + p.x * sv.y) * scale;
            if (!isfinite(o0)) o0 = 0.f;
            if (!isfinite(o1)) o1 = 0.f;
            unsigned u = (unsigned)f2bu(o0) | ((unsigned)f2bu(o1) << 16);
            *(unsigned*)(dst + (size_t)rowG * E_ + cbase + col0) = u;
        }
    } else if (colBase < 4096) {
        // v: transposed store into vt
        const int colW = colBase + wc * 64;
        #pragma unroll
        for (int m = 0; m < 4; ++m)
            #pragma unroll
            for (int n = 0; n < 4; ++n) {
                const int row0 = rowBase + wr * 64 + m * 16 + (l >> 4) * 4;
                const int vcol = colW + n * 16 + (l & 15) - 2048;
                const int vbatch = row0 >> 11;
                const int t0 = row0 & (T_ - 1);
                unsigned short pk[4];
                #pragma unroll
                for (int r = 0; r < 4; ++r) {
                    float f = acc[m][n][r];
                    if (!isfinite(f)) f = 0.f;
                    pk[r] = f2bu(f);
                }
                *(ushort4*)(vt + (size_t)(vbatch * V_ + vcol) * T_ + t0) =
                    make_ushort4(pk[0], pk[1], pk[2], pk[3]);
            }
    } else {
        // g: direct store
        const int colW = colBase + wc * 64;
        #pragma unroll
        for (int m = 0; m < 4; ++m)
            #pragma unroll
            for (int n = 0; n < 4; ++n)
                #pragma unroll
                for (int r = 0; r < 4; ++r) {
                    int row = rowBase + wr * 64 + m * 16 + (l >> 4) * 4 + r;
                    int col = colW + n * 16 + (l & 15);
                    float f = acc[m][n][r];
                    if (!isfinite(f)) f = 0.f;
                    gb[(size_t)row * V_ + (col - 4096)] = f2bu(f);
                }
    }
}

// ---------------------------------------------------------------------------
// Wo GEMM, 64x128 tile.  [2D grid (8,64)]
// ---------------------------------------------------------------------------
__global__ __launch_bounds__(256) void gemm_wo_kernel(
    const unsigned short* __restrict__ A,
    const unsigned short* __restrict__ Bt,
    float* __restrict__ C)
{
    const int K = V_;   // 2048
    __shared__ __align__(16) char Asm[2][64 * 128];
    __shared__ __align__(16) char Bsm[2][128 * 128];
    const int tid = threadIdx.x;
    const int l = tid & 63;
    const int w = tid >> 6;
    const int wr = w >> 1, wc = w & 1;
    const int rowBase = blockIdx.y * 64;
    const int colBase = blockIdx.x * 128;
    const int srow = tid >> 3;
    const int scolb = (tid & 7) * 16;

    f32x4 acc[2][4] = {};

#define WSTAGE(BUF, K0)                                                        \
    {                                                                          \
        _Pragma("unroll")                                                      \
        for (int i = 0; i < 2; ++i) {                                          \
            int r = i * 32 + srow;                                             \
            int cb = scolb ^ ((r & 7) << 4);                                   \
            gl_lds16((const char*)(A + (size_t)(rowBase + r) * K + (K0)) + cb, \
                     Asm[BUF] + i * 4096 + w * 1024);                          \
        }                                                                      \
        _Pragma("unroll")                                                      \
        for (int i = 0; i < 4; ++i) {                                          \
            int r = i * 32 + srow;                                             \
            int cb = scolb ^ ((r & 7) << 4);                                   \
            gl_lds16((const char*)(Bt + (size_t)(colBase + r) * K + (K0)) + cb,\
                     Bsm[BUF] + i * 4096 + w * 1024);                          \
        }                                                                      \
    }

    WSTAGE(0, 0)
    const int nk = K / 64;   // 32
    for (int kt = 0; kt < nk; ++kt) {
        const int cur = kt & 1;
        if (kt + 1 < nk) {
            WSTAGE(1 - cur, (kt + 1) * 64)
            asm volatile("s_waitcnt vmcnt(6)" ::: "memory");
        } else {
            asm volatile("s_waitcnt vmcnt(0)" ::: "memory");
        }
        __builtin_amdgcn_s_barrier();
        __builtin_amdgcn_sched_barrier(0);
        #pragma unroll
        for (int kk = 0; kk < 2; ++kk) {
            const int cb = kk * 64 + (l >> 4) * 16;
            bf16x8 a[2], b[4];
            #pragma unroll
            for (int m = 0; m < 2; ++m) {
                int r = wr * 32 + m * 16 + (l & 15);
                a[m] = *(const bf16x8*)(Asm[cur] + r * 128 + (cb ^ ((r & 7) << 4)));
            }
            #pragma unroll
            for (int n = 0; n < 4; ++n) {
                int r = wc * 64 + n * 16 + (l & 15);
                b[n] = *(const bf16x8*)(Bsm[cur] + r * 128 + (cb ^ ((r & 7) << 4)));
            }
            #pragma unroll
            for (int m = 0; m < 2; ++m)
                #pragma unroll
                for (int n = 0; n < 4; ++n)
                    acc[m][n] = __builtin_amdgcn_mfma_f32_16x16x32_bf16(a[m], b[n], acc[m][n], 0, 0, 0);
        }
        __builtin_amdgcn_s_barrier();
        __builtin_amdgcn_sched_barrier(0);
    }
#undef WSTAGE

    #pragma unroll
    for (int m = 0; m < 2; ++m)
        #pragma unroll
        for (int n = 0; n < 4; ++n)
            #pragma unroll
            for (int r = 0; r < 4; ++r) {
                int row = rowBase + wr * 32 + m * 16 + (l >> 4) * 4 + r;
                int col = colBase + wc * 64 + n * 16 + (l & 15);
                float f = acc[m][n][r];
                if (!isfinite(f)) f = 0.f;
                C[(size_t)row * E_ + col] = f;
            }
}

// ---------------------------------------------------------------------------
// Retention v6: swapped operands, column PV, complementarity pairing,
// factorized decay, fused rms_silu epilogue.
// ---------------------------------------------------------------------------
#define STAGE_K(BUF, T0)                                                       \
    {                                                                          \
        _Pragma("unroll")                                                      \
        for (int i = 0; i < 4; ++i) {                                          \
            int r = i * 16 + (tid >> 4);                                       \
            int cb = ((tid & 15) * 16) ^ ((r & 7) << 4);                       \
            gl_lds16((const char*)(kb + (size_t)(b * T_ + (T0) + r) * E_ + h * KD_) + cb, \
                     Ks[BUF] + i * 4096 + w * 1024);                           \
        }                                                                      \
    }

#define STAGE_V(T0)                                                            \
    {                                                                          \
        _Pragma("unroll")                                                      \
        for (int i = 0; i < 8; ++i) {                                          \
            int r = i * 32 + (tid >> 3);                                       \
            int cb = ((tid & 7) * 16) ^ ((r & 7) << 4);                        \
            gl_lds16((const char*)(vt + (size_t)((b * H_ + h) * HD_ + r) * T_ + (T0)) + cb, \
                     Vs + i * 4096 + w * 1024);                                \
        }                                                                      \
    }

__global__ __launch_bounds__(256, 2) void retention_mfma_kernel(
    const unsigned short* __restrict__ qb,
    const unsigned short* __restrict__ kb,
    const unsigned short* __restrict__ vt,
    const unsigned short* __restrict__ g,
    unsigned short* __restrict__ ao)
{
    __shared__ __align__(16) char Ks[2][64 * 128 * 2];   // 2 x 16 KB
    __shared__ __align__(16) char Vs[256 * 64 * 2];      //     32 KB
    __shared__ __align__(16) char Pq[64 * 64 * 2];       //      8 KB [q][t]
    __shared__ float rsum_p[4][64];
    __shared__ float rsq_p[4][64];
    const int tid = threadIdx.x;
    const int l = tid & 63;
    const int w = tid >> 6;
    const int g_ = l >> 4;
    const int q15 = l & 15;
    const int orig = (int)blockIdx.x;
    const int xcd  = orig & 7;
    const int pos  = orig >> 3;
    const int slot = pos >> 5;
    const int cu   = pos & 31;
    const int half = cu >> 4;
    const int c15  = cu & 15;
    const int bh   = xcd * 2 + half;
    const int chunk = slot ? c15 : (31 - c15);
    const int b = bh >> 3, h = bh & 7;
    const int s0 = chunk * 64;
    const float ld = logf(1.f - exp2f(-5.f - (float)h));

    float es[4];
    #pragma unroll
    for (int qb2 = 0; qb2 < 4; ++qb2)
        es[qb2] = __expf((float)(s0 + qb2 * 16 + q15) * ld);
    float etl[4];
    #pragma unroll
    for (int r = 0; r < 4; ++r)
        etl[r] = __expf(-(float)(w * 16 + 4 * g_ + r) * ld);
    const float Dm64 = __expf(-64.f * ld);
    float etb = 1.f;

    bf16x8 qf[4][4];
    #pragma unroll
    for (int qb2 = 0; qb2 < 4; ++qb2) {
        const char* qp = (const char*)(qb + (size_t)(b * T_ + s0 + qb2 * 16 + q15) * E_ + h * KD_);
        #pragma unroll
        for (int kk = 0; kk < 4; ++kk)
            qf[qb2][kk] = *(const bf16x8*)(qp + kk * 64 + g_ * 16);
    }

    f32x4 oaccT[4][4] = {};
    float rs[4] = {0.f, 0.f, 0.f, 0.f};

    const int nt = chunk + 1;
    STAGE_K(0, 0)

    for (int t = 0; t < nt; ++t) {
        const int cur = t & 1;
        const int t0 = t * 64;
        STAGE_V(t0)
        if (t + 1 < nt) {
            STAGE_K(1 - cur, t0 + 64)
            asm volatile("s_waitcnt vmcnt(12)" ::: "memory");
        } else {
            asm volatile("s_waitcnt vmcnt(8)" ::: "memory");
        }
        __builtin_amdgcn_s_barrier();
        __builtin_amdgcn_sched_barrier(0);

        f32x4 sacc[4] = {};
        {
            const int krow = w * 16 + q15;
            const int swz = (krow & 7) << 4;
            #pragma unroll
            for (int kk = 0; kk < 4; ++kk) {
                bf16x8 kf = *(const bf16x8*)(Ks[cur] + krow * 256 + ((kk * 64 + g_ * 16) ^ swz));
                #pragma unroll
                for (int qb2 = 0; qb2 < 4; ++qb2)
                    sacc[qb2] = __builtin_amdgcn_mfma_f32_16x16x32_bf16(kf, qf[qb2][kk], sacc[qb2], 0, 0, 0);
            }
        }
        {
            const float etw = etb;
            #pragma unroll
            for (int qb2 = 0; qb2 < 4; ++qb2) {
                const int qg = s0 + qb2 * 16 + q15;
                const int q_local = qb2 * 16 + q15;
                float rsp = 0.f;
                unsigned short pk[4];
                #pragma unroll
                for (int r = 0; r < 4; ++r) {
                    int tg = t0 + w * 16 + 4 * g_ + r;
                    float pm = (qg >= tg) ? sacc[qb2][r] * (es[qb2] * etw * etl[r]) : 0.f;
                    rsp += pm;
                    pk[r] = f2bu(pm);
                }
                *(ushort4*)(Pq + q_local * 128 + (((w * 16 + 4 * g_) * 2) ^ ((q_local & 7) << 4))) =
                    make_ushort4(pk[0], pk[1], pk[2], pk[3]);
                rsp += __shfl_xor(rsp, 16);
                rsp += __shfl_xor(rsp, 32);
                rs[qb2] += rsp;
            }
            etb *= Dm64;
        }
        if (t + 1 < nt) {
            asm volatile("s_waitcnt vmcnt(4) lgkmcnt(0)" ::: "memory");
        } else {
            asm volatile("s_waitcnt vmcnt(0) lgkmcnt(0)" ::: "memory");
        }
        __builtin_amdgcn_s_barrier();
        __builtin_amdgcn_sched_barrier(0);
        #pragma unroll
        for (int kk = 0; kk < 2; ++kk) {
            const int cb = kk * 64 + g_ * 16;
            bf16x8 pf[4], vf[4];
            #pragma unroll
            for (int qb2 = 0; qb2 < 4; ++qb2) {
                int pr = qb2 * 16 + q15;
                pf[qb2] = *(const bf16x8*)(Pq + pr * 128 + (cb ^ ((pr & 7) << 4)));
            }
            #pragma unroll
            for (int m = 0; m < 4; ++m) {
                int vr = w * 64 + m * 16 + q15;
                vf[m] = *(const bf16x8*)(Vs + vr * 128 + (cb ^ ((vr & 7) << 4)));
            }
            #pragma unroll
            for (int qb2 = 0; qb2 < 4; ++qb2)
                #pragma unroll
                for (int m = 0; m < 4; ++m)
                    oaccT[qb2][m] = __builtin_amdgcn_mfma_f32_16x16x32_bf16(vf[m], pf[qb2], oaccT[qb2][m], 0, 0, 0);
        }
        __builtin_amdgcn_s_barrier();
        __builtin_amdgcn_sched_barrier(0);
    }

    if (l < 16) {
        #pragma unroll
        for (int qb2 = 0; qb2 < 4; ++qb2)
            rsum_p[w][qb2 * 16 + q15] = rs[qb2];
    }
    __syncthreads();

    float inv[4];
    #pragma unroll
    for (int qb2 = 0; qb2 < 4; ++qb2) {
        const int q_local = qb2 * 16 + q15;
        const float tot = rsum_p[0][q_local] + rsum_p[1][q_local] +
                          rsum_p[2][q_local] + rsum_p[3][q_local];
        inv[qb2] = 1.f / fmaxf(fabsf(tot), 1.f);
    }

    #pragma unroll
    for (int qb2 = 0; qb2 < 4; ++qb2) {
        float ps = 0.f;
        #pragma unroll
        for (int m = 0; m < 4; ++m)
            #pragma unroll
            for (int r = 0; r < 4; ++r) {
                float o = oaccT[qb2][m][r] * inv[qb2];
                ps += o * o;
            }
        ps += __shfl_xor(ps, 16);
        ps += __shfl_xor(ps, 32);
        if (l < 16) rsq_p[w][qb2 * 16 + q15] = ps;
    }
    __syncthreads();

    #pragma unroll
    for (int qb2 = 0; qb2 < 4; ++qb2) {
        const int q_local = qb2 * 16 + q15;
        const float tot = rsq_p[0][q_local] + rsq_p[1][q_local] +
                          rsq_p[2][q_local] + rsq_p[3][q_local];
        const float scale = rsqrtf(tot * (1.0f / HD_) + 1e-6f) * inv[qb2];
        const size_t rowb = (size_t)(b * T_ + s0 + q_local) * V_ + h * HD_;
        #pragma unroll
        for (int m = 0; m < 4; ++m) {
            const int vc0 = w * 64 + m * 16 + 4 * g_;
            ushort4 gv4 = *(const ushort4*)(g + rowb + vc0);
            const unsigned short* gv = (const unsigned short*)&gv4;
            unsigned short outp[4];
            #pragma unroll
            for (int r = 0; r < 4; ++r) {
                const float gvf = u2f(gv[r]);
                const float silu = gvf / (1.f + __expf(-gvf));
                float f = oaccT[qb2][m][r] * scale * silu;
                if (!isfinite(f)) f = 0.f;
                outp[r] = f2bu(f);
            }
            *(ushort4*)(ao + rowb + vc0) = make_ushort4(outp[0], outp[1], outp[2], outp[3]);
        }
    }
}

extern "C" void kernel_launch(void* const* d_in, const int* in_sizes, int n_in,
                              void* d_out, int out_size, void* d_ws, size_t ws_size,
                              hipStream_t stream)
{
    const float* x    = (const float*)d_in[0];
    const float* sinp = (const float*)d_in[1];
    const float* cosp = (const float*)d_in[2];
    // d_in[3] = mask: decay computed analytically in-kernel
    const float* Wq   = (const float*)d_in[4];
    const float* Wk   = (const float*)d_in[5];
    const float* Wv   = (const float*)d_in[6];
    const float* Wg   = (const float*)d_in[7];
    const float* Wo   = (const float*)d_in[8];
    float* out = (float*)d_out;

    // d_out doubles as scratch (R4-proven): xb [0,8.39M) | qb [8.39M,16.78M).
    unsigned short* xb = (unsigned short*)d_out;
    unsigned short* qb = xb + (size_t)M_ * E_;

    // ws: DISJOINT layout (~75 MB of 512 MiB).
    char* ws = (char*)d_ws;
    unsigned short* kb  = (unsigned short*)(ws + 0);         //  8.39 MB
    unsigned short* gb  = (unsigned short*)(ws + 8388608);   // 16.78 MB
    unsigned short* wt  = (unsigned short*)(ws + 25165824);  // 12.58 MB [6144][1024]
    unsigned short* vt  = (unsigned short*)(ws + 37748736);  // 16.78 MB [B*2048][T]
    unsigned short* aob = (unsigned short*)(ws + 54525952);  // 16.78 MB
    unsigned short* wot = (unsigned short*)(ws + 71303168);  //  4.19 MB

    dim3 blk(256);
    transW6_kernel<<<dim3(32, 32, 6), blk, 0, stream>>>(Wq, Wk, Wv, Wg, Wo, x, wt, wot, xb);

    gemm_qkvg_kernel<<<dim3(48, 32), blk, 0, stream>>>(xb, wt, sinp, cosp, qb, kb, vt, gb);

    retention_mfma_kernel<<<dim3(512), blk, 0, stream>>>(qb, kb, vt, gb, aob);

    gemm_wo_kernel<<<dim3(8, 64), blk, 0, stream>>>(aob, wot, out);
}